// Round 4
// baseline (147.760 us; speedup 1.0000x reference)
//
#include <hip/hip_runtime.h>
#include <stdint.h>

#define T_LEN 2048
// (1/8) softmax scale * (1/ln2) folded into Q at prepack: exp(s/8) = exp2(q'.k)
#define QSCALE 0.18033688011112042f

typedef __attribute__((ext_vector_type(8))) short bf16x8;
typedef __attribute__((ext_vector_type(16))) float f32x16;

// RNE fp32 pair -> packed bf16x2 (inputs finite normals)
static __device__ __forceinline__ unsigned pack_bf16(float a, float b) {
    unsigned ua = __float_as_uint(a);
    unsigned ub = __float_as_uint(b);
    ua = (ua + 0x7fffu + ((ua >> 16) & 1u)) >> 16;
    ub = (ub + 0x7fffu + ((ub >> 16) & 1u));
    return (ua & 0xffffu) | (ub & 0xffff0000u);
}

// async global->LDS DMA, 16 B/lane: LDS dest = wave-uniform base + lane*16
static __device__ __forceinline__ void async16(const void* g, void* l) {
    __builtin_amdgcn_global_load_lds(
        (const __attribute__((address_space(1))) unsigned int*)g,
        (__attribute__((address_space(3))) unsigned int*)l, 16, 0, 0);
}

// ---------------------------------------------------------------------------
// Prepack (all LDS phases conflict-free via 16B-chunk XOR swizzle):
//   Q: ws+0     bf16 [head][t][swz c] rows 128B, scaled by QSCALE
//   K: ws+8MB   bf16 [head][s][swz c] rows 128B
//   V: ws+16MB  bf16 [head][sTile(64)][c][swz s] rows 128B
// ---------------------------------------------------------------------------
__global__ __launch_bounds__(256)
void prepack(const float* __restrict__ qkv, char* __restrict__ ws)
{
    __shared__ float tile[8192];          // 64 c x 32 chunks(16B) of t, swizzled
    const int tid = threadIdx.x;
    const int b = blockIdx.x;

    if (b < 1024) {                       // ---- Q / K transpose (128 t x 64 c)
        const int isK  = b >> 9;
        const int bb   = b & 511;
        const int head = bb >> 4, chunk = bb & 15;
        const float* src = qkv + (size_t)head * 192 * T_LEN
                               + (isK ? (size_t)64 * T_LEN : 0);
        const int t0 = chunk * 128;
        const float scale = isK ? 1.0f : QSCALE;
        // stage: lane writes float4; chunks (t4^(c&7)) span all 8 bank groups
#pragma unroll
        for (int i = 0; i < 8; ++i) {
            int p = i * 256 + tid;
            int c = p >> 5, t4 = p & 31;
            float4 v = *(const float4*)(src + (size_t)c * T_LEN + t0 + 4 * t4);
            *(float4*)&tile[c * 128 + ((t4 ^ (c & 7)) << 2)] = v;
        }
        __syncthreads();
        unsigned* dst = (unsigned*)ws + (size_t)isK * 2097152
                      + (size_t)head * 65536 + (size_t)t0 * 32;
        const int c = tid & 63, cp = c >> 1, odd = c & 1;
#pragma unroll
        for (int jj = 0; jj < 8; ++jj) {
            int j = jj * 4 + (tid >> 6);  // wave-uniform t-chunk 0..31
            float4 m = *(const float4*)&tile[c * 128 + ((j ^ (c & 7)) << 2)];
            m.x *= scale; m.y *= scale; m.z *= scale; m.w *= scale;
            float tx = __shfl_xor(m.x, 1), ty = __shfl_xor(m.y, 1);
            float tz = __shfl_xor(m.z, 1), tw = __shfl_xor(m.w, 1);
            unsigned d0, d1; int te;
            if (!odd) { d0 = pack_bf16(m.x, tx); d1 = pack_bf16(m.y, ty); te = 4 * j; }
            else      { d0 = pack_bf16(tz, m.z); d1 = pack_bf16(tw, m.w); te = 4 * j + 2; }
            dst[te * 32 + (((cp >> 2) ^ (te & 7)) << 2) + (cp & 3)] = d0;
            int tf = te + 1;
            dst[tf * 32 + (((cp >> 2) ^ (tf & 7)) << 2) + (cp & 3)] = d1;
        }
    } else {                              // ---- V pass-through (swizzle only)
        const int b3 = b - 1024;
        const int head = b3 >> 5, st = b3 & 31;
        const float* src = qkv + (size_t)head * 192 * T_LEN + (size_t)128 * T_LEN;
        const int s0 = st * 64;
        unsigned* dst = (unsigned*)(ws + 16777216) + (size_t)b3 * 2048;
#pragma unroll
        for (int i = 0; i < 8; ++i) {
            int p = i * 256 + tid;
            int s2 = p & 31, cc = p >> 5;
            float2 v = *(const float2*)(src + (size_t)cc * T_LEN + s0 + 2 * s2);
            dst[cc * 32 + (((s2 >> 2) ^ (cc & 7)) << 2) + (s2 & 3)] = pack_bf16(v.x, v.y);
        }
    }
}

// ---------------------------------------------------------------------------
// Main: flash attention, 32x32x16 MFMA, S^T orientation, register-only P
// transform (xor-32 exchange), 2t x 2s wave split, STILE=128 (16 iters),
// double-buffered K/V; V[1] aliases dead Q; epilogue aliases dead K/V.
// ---------------------------------------------------------------------------
__global__ __launch_bounds__(256, 2)
void attn_fwd(const char* __restrict__ ws, float* __restrict__ out)
{
    __shared__ char smem[65536];
    // [0,16384)      Qs  (dead after qf) = Vs[1]
    // [16384,49152)  Ks[0], Ks[1]        (epilogue: Ob 32 KB)
    // [49152,65536)  Vs[0]               (epilogue: Lb 1 KB)
    char*  Qs  = smem;
    char*  Ks0 = smem + 16384;
    char*  Vs0 = smem + 49152;
    float* Ob  = (float*)(smem + 16384);
    float* Lb  = (float*)(smem + 49152);

    const int tid  = threadIdx.x;
    const int wave = tid >> 6, lane = tid & 63;
    const int l31  = lane & 31, h = lane >> 5;
    const int wt   = wave & 1;            // t-half (64 t)
    const int wsx  = wave >> 1;           // s-half (64 s per iter)
    const int head = blockIdx.x & 31, tb = blockIdx.x >> 5;
    const int swq  = l31 & 7;

    const char* qsrc = ws + (size_t)head * 262144 + (size_t)tb * 16384;
    const char* ksrc = ws + 8388608  + (size_t)head * 262144;
    const char* vsrc = ws + 16777216 + (size_t)head * 262144;

    // prologue staging: Q + K tile0 + V tile0 (16 KB each, 4 chunks/wave)
#pragma unroll
    for (int n = 0; n < 4; ++n) {
        int ch = wave * 4 + n;
        async16(qsrc + ch * 1024 + lane * 16, Qs  + ch * 1024);
        async16(ksrc + ch * 1024 + lane * 16, Ks0 + ch * 1024);
        async16(vsrc + ch * 1024 + lane * 16, Vs0 + ch * 1024);
    }
    __syncthreads();

    // Q fragments (B operand): rows t = wt*64 + tt*32 + l31
    bf16x8 qf[2][4];
#pragma unroll
    for (int tt = 0; tt < 2; ++tt)
#pragma unroll
        for (int kb = 0; kb < 4; ++kb)
            qf[tt][kb] = *(const bf16x8*)(Qs + (wt * 64 + tt * 32 + l31) * 128
                                          + (((kb * 2 + h) ^ swq) << 4));
    __syncthreads();                      // protect Qs until all qf loaded (V[1] alias)

    f32x16 acc[2][2];                     // [ct][tt] O^T[c][t] partial (s-half)
#pragma unroll
    for (int ct = 0; ct < 2; ++ct)
#pragma unroll
        for (int tt = 0; tt < 2; ++tt)
#pragma unroll
            for (int r = 0; r < 16; ++r) acc[ct][tt][r] = 0.f;
    float lp0 = 0.f, lp1 = 0.f;

    for (int i = 0; i < 16; ++i) {
        const int cur = i & 1, nxt = cur ^ 1;
        if (i) __syncthreads();
        if (i < 15) {                     // prefetch tile i+1 (K,V 16 KB each)
            const char* kg = ksrc + (size_t)(i + 1) * 16384;
            const char* vg = vsrc + (size_t)(i + 1) * 16384;
            char* kd = Ks0 + nxt * 16384;
            char* vd = nxt ? Qs : Vs0;
#pragma unroll
            for (int n = 0; n < 4; ++n) {
                int ch = wave * 4 + n;
                async16(kg + ch * 1024 + lane * 16, kd + ch * 1024);
                async16(vg + ch * 1024 + lane * 16, vd + ch * 1024);
            }
        }
        const char* KsB = Ks0 + cur * 16384;
        const char* VsB = cur ? Qs : Vs0;

#pragma unroll
        for (int sr = 0; sr < 2; ++sr) {  // two 32-s row groups of this wave's 64 s
            // ---- QK^T (A=K): S^T rows s, cols t (Q pre-scaled by 1/(8 ln2))
            f32x16 sc0, sc1;
#pragma unroll
            for (int r = 0; r < 16; ++r) { sc0[r] = 0.f; sc1[r] = 0.f; }
            const int krow = (wsx * 64 + sr * 32 + l31) * 128;
#pragma unroll
            for (int kb = 0; kb < 4; ++kb) {
                bf16x8 kf = *(const bf16x8*)(KsB + krow + (((kb * 2 + h) ^ swq) << 4));
                sc0 = __builtin_amdgcn_mfma_f32_32x32x16_bf16(kf, qf[0][kb], sc0, 0, 0, 0);
                sc1 = __builtin_amdgcn_mfma_f32_32x32x16_bf16(kf, qf[1][kb], sc1, 0, 0, 0);
            }

            // ---- softmax (no max-sub) via exp2 + bf16 truncation pack;
            //      l accumulated from TRUNCATED values so weights sum exactly
            unsigned p0[8], p1[8];
#pragma unroll
            for (int d = 0; d < 8; ++d) {
                unsigned a0 = __float_as_uint(exp2f(sc0[2 * d]))     & 0xffff0000u;
                unsigned a1 = __float_as_uint(exp2f(sc0[2 * d + 1])) & 0xffff0000u;
                lp0 += __uint_as_float(a0) + __uint_as_float(a1);
                p0[d] = __builtin_amdgcn_perm(a1, a0, 0x07060302u);
                unsigned b0 = __float_as_uint(exp2f(sc1[2 * d]))     & 0xffff0000u;
                unsigned b1 = __float_as_uint(exp2f(sc1[2 * d + 1])) & 0xffff0000u;
                lp1 += __uint_as_float(b0) + __uint_as_float(b1);
                p1[d] = __builtin_amdgcn_perm(b1, b0, 0x07060302u);
            }

            // ---- xor-32 exchange: C-layout -> B-layout
            unsigned u00 = __shfl_xor(h ? p0[0] : p0[2], 32);
            unsigned u01 = __shfl_xor(h ? p0[1] : p0[3], 32);
            unsigned u02 = __shfl_xor(h ? p0[4] : p0[6], 32);
            unsigned u03 = __shfl_xor(h ? p0[5] : p0[7], 32);
            unsigned u10 = __shfl_xor(h ? p1[0] : p1[2], 32);
            unsigned u11 = __shfl_xor(h ? p1[1] : p1[3], 32);
            unsigned u12 = __shfl_xor(h ? p1[4] : p1[6], 32);
            unsigned u13 = __shfl_xor(h ? p1[5] : p1[7], 32);

            union PF { unsigned u[4]; bf16x8 v; };
            PF f00, f01, f10, f11;        // [tt][kb2i]
            f00.u[0] = h ? u00 : p0[0]; f00.u[1] = h ? u01 : p0[1];
            f00.u[2] = h ? p0[2] : u00; f00.u[3] = h ? p0[3] : u01;
            f01.u[0] = h ? u02 : p0[4]; f01.u[1] = h ? u03 : p0[5];
            f01.u[2] = h ? p0[6] : u02; f01.u[3] = h ? p0[7] : u03;
            f10.u[0] = h ? u10 : p1[0]; f10.u[1] = h ? u11 : p1[1];
            f10.u[2] = h ? p1[2] : u10; f10.u[3] = h ? p1[3] : u11;
            f11.u[0] = h ? u12 : p1[4]; f11.u[1] = h ? u13 : p1[5];
            f11.u[2] = h ? p1[6] : u12; f11.u[3] = h ? p1[7] : u13;

            // ---- PV: O^T[c][t] += V[c][s] * P[t][s] over this 32-s group
#pragma unroll
            for (int kb2i = 0; kb2i < 2; ++kb2i) {
                const int kc = wsx * 4 + sr * 2 + kb2i;        // 16-s chunk id
                const int voff = (kc >> 2) * 8192
                               + (((((kc & 3) * 2) + h) ^ swq) << 4);
                const bf16x8 pfv0 = kb2i ? f01.v : f00.v;
                const bf16x8 pfv1 = kb2i ? f11.v : f10.v;
#pragma unroll
                for (int ct = 0; ct < 2; ++ct) {
                    bf16x8 vf = *(const bf16x8*)(VsB + voff + (ct * 32 + l31) * 128);
                    acc[ct][0] = __builtin_amdgcn_mfma_f32_32x32x16_bf16(vf, pfv0, acc[ct][0], 0, 0, 0);
                    acc[ct][1] = __builtin_amdgcn_mfma_f32_32x32x16_bf16(vf, pfv1, acc[ct][1], 0, 0, 0);
                }
            }
        }
    }

    __syncthreads();                      // all LDS compute reads done

    // ---- l: reduce over h, publish per s-half (Lb aliases dead Vs0)
    float lt0 = lp0 + __shfl_xor(lp0, 32);
    float lt1 = lp1 + __shfl_xor(lp1, 32);
    if (h == 0) {
        Lb[wsx * 128 + wt * 64 + l31]      = lt0;
        Lb[wsx * 128 + wt * 64 + 32 + l31] = lt1;
    }
    // ---- O: s-half-1 waves stash partials (Ob aliases dead Ks)
    if (wsx == 1) {
#pragma unroll
        for (int ct = 0; ct < 2; ++ct)
#pragma unroll
            for (int tt = 0; tt < 2; ++tt)
#pragma unroll
                for (int r = 0; r < 16; ++r) {
                    int c = ct * 32 + (r & 3) + 8 * (r >> 2) + 4 * h;
                    Ob[c * 128 + wt * 64 + tt * 32 + l31] = acc[ct][tt][r];
                }
    }
    __syncthreads();

    if (wsx == 0) {
        const float li0 = 1.0f / (Lb[wt * 64 + l31] + Lb[128 + wt * 64 + l31]);
        const float li1 = 1.0f / (Lb[wt * 64 + 32 + l31] + Lb[128 + wt * 64 + 32 + l31]);
#pragma unroll
        for (int ct = 0; ct < 2; ++ct)
#pragma unroll
            for (int tt = 0; tt < 2; ++tt) {
                const float li = tt ? li1 : li0;
#pragma unroll
                for (int r = 0; r < 16; ++r) {
                    int c = ct * 32 + (r & 3) + 8 * (r >> 2) + 4 * h;
                    float v = acc[ct][tt][r] + Ob[c * 128 + wt * 64 + tt * 32 + l31];
                    out[((size_t)head * 64 + c) * T_LEN + tb * 128 + wt * 64 + tt * 32 + l31]
                        = v * li;
                }
            }
    }
}

extern "C" void kernel_launch(void* const* d_in, const int* in_sizes, int n_in,
                              void* d_out, int out_size, void* d_ws, size_t ws_size,
                              hipStream_t stream) {
    const float* qkv = (const float*)d_in[0];
    float* out = (float*)d_out;
    char* ws = (char*)d_ws;   // 24 MB
    hipLaunchKernelGGL(prepack, dim3(2048), dim3(256), 0, stream, qkv, ws);
    hipLaunchKernelGGL(attn_fwd, dim3(512), dim3(256), 0, stream, ws, out);
}

// Round 5
// 138.179 us; speedup vs baseline: 1.0693x; 1.0693x over previous
//
#include <hip/hip_runtime.h>
#include <stdint.h>

#define T_LEN 2048
#define QSCALE 0.125f   // softmax scale folded into Q at prepack (exact pow2)

typedef __attribute__((ext_vector_type(8))) short bf16x8;
typedef __attribute__((ext_vector_type(16))) float f32x16;

// RNE fp32 pair -> packed bf16x2 (inputs finite normals)
static __device__ __forceinline__ unsigned pack_bf16(float a, float b) {
    unsigned ua = __float_as_uint(a);
    unsigned ub = __float_as_uint(b);
    ua = (ua + 0x7fffu + ((ua >> 16) & 1u)) >> 16;
    ub = (ub + 0x7fffu + ((ub >> 16) & 1u));
    return (ua & 0xffffu) | (ub & 0xffff0000u);
}

// async global->LDS DMA, 16 B/lane: LDS dest = wave-uniform base + lane*16
static __device__ __forceinline__ void async16(const void* g, void* l) {
    __builtin_amdgcn_global_load_lds(
        (const __attribute__((address_space(1))) unsigned int*)g,
        (__attribute__((address_space(3))) unsigned int*)l, 16, 0, 0);
}

// ---------------------------------------------------------------------------
// Prepack:
//   Q: ws+0     bf16 [head][t][swz c] rows 128B, scaled by QSCALE
//   K: ws+8MB   bf16 [head][s][swz c] rows 128B
//   V: ws+16MB  bf16 [head][sTile(64)][c][swz s] rows 128B
// LDS transpose tile stride 129 floats: c*129 mod 32 = c, so the 8 lanes
// sharing c&7 in phase 2 split 4 bank offsets -> 2-way (free). Phase 1 ditto.
// ---------------------------------------------------------------------------
__global__ __launch_bounds__(256)
void prepack(const float* __restrict__ qkv, char* __restrict__ ws)
{
    __shared__ float tile[64 * 129];
    const int tid = threadIdx.x;
    const int b = blockIdx.x;

    if (b < 1024) {                       // ---- Q / K transpose (128 t x 64 c)
        const int isK  = b >> 9;
        const int bb   = b & 511;
        const int head = bb >> 4, chunk = bb & 15;
        const float* src = qkv + (size_t)head * 192 * T_LEN
                               + (isK ? (size_t)64 * T_LEN : 0);
        const int t0 = chunk * 128;
        const float scale = isK ? 1.0f : QSCALE;
#pragma unroll
        for (int i = 0; i < 8; ++i) {
            int p = i * 256 + tid;
            int c = p >> 5, t4 = p & 31;
            float4 v = *(const float4*)(src + (size_t)c * T_LEN + t0 + 4 * t4);
            *(float4*)&tile[c * 129 + ((t4 ^ (c & 7)) << 2)] = v;
        }
        __syncthreads();
        unsigned* dst = (unsigned*)ws + (size_t)isK * 2097152
                      + (size_t)head * 65536 + (size_t)t0 * 32;
        const int c = tid & 63, cp = c >> 1, odd = c & 1;
#pragma unroll
        for (int jj = 0; jj < 8; ++jj) {
            int j = jj * 4 + (tid >> 6);  // wave-uniform t-chunk 0..31
            float4 m = *(const float4*)&tile[c * 129 + ((j ^ (c & 7)) << 2)];
            m.x *= scale; m.y *= scale; m.z *= scale; m.w *= scale;
            float tx = __shfl_xor(m.x, 1), ty = __shfl_xor(m.y, 1);
            float tz = __shfl_xor(m.z, 1), tw = __shfl_xor(m.w, 1);
            unsigned d0, d1; int te;
            if (!odd) { d0 = pack_bf16(m.x, tx); d1 = pack_bf16(m.y, ty); te = 4 * j; }
            else      { d0 = pack_bf16(tz, m.z); d1 = pack_bf16(tw, m.w); te = 4 * j + 2; }
            dst[te * 32 + (((cp >> 2) ^ (te & 7)) << 2) + (cp & 3)] = d0;
            int tf = te + 1;
            dst[tf * 32 + (((cp >> 2) ^ (tf & 7)) << 2) + (cp & 3)] = d1;
        }
    } else {                              // ---- V pass-through (swizzle only)
        const int b3 = b - 1024;
        const int head = b3 >> 5, st = b3 & 31;
        const float* src = qkv + (size_t)head * 192 * T_LEN + (size_t)128 * T_LEN;
        const int s0 = st * 64;
        unsigned* dst = (unsigned*)(ws + 16777216) + (size_t)b3 * 2048;
#pragma unroll
        for (int i = 0; i < 8; ++i) {
            int p = i * 256 + tid;
            int s2 = p & 31, cc = p >> 5;
            float2 v = *(const float2*)(src + (size_t)cc * T_LEN + s0 + 2 * s2);
            dst[cc * 32 + (((s2 >> 2) ^ (cc & 7)) << 2) + (s2 & 3)] = pack_bf16(v.x, v.y);
        }
    }
}

// ---------------------------------------------------------------------------
// Main: flash attention, 32x32x16 MFMA, S^T orientation, register-only P
// transform (xor-32 exchange). TTILE=64: 1024 blocks x 40 KB LDS
// -> 4 blocks/CU = 16 waves/CU for latency hiding. 2t x 2s wave split,
// STILE=64, double-buffered K/V via async DMA. All 32 blocks of a head
// share bid%8 -> head K/V pinned to one XCD L2.
// ---------------------------------------------------------------------------
__global__ __launch_bounds__(256, 4)
void attn_fwd(const char* __restrict__ ws, float* __restrict__ out)
{
    __shared__ char smem[40960];
    // [0,8192)       Qs (64 t x 128B)
    // [8192,24576)   Ks[2]   (epilogue: Ob 16 KB)
    // [24576,40960)  Vs[2]   (epilogue: Lb 512 B)
    char*  Qs  = smem;
    char*  Ks0 = smem + 8192;
    char*  Vs0 = smem + 24576;
    float* Ob  = (float*)(smem + 8192);
    float* Lb  = (float*)(smem + 24576);

    const int tid  = threadIdx.x;
    const int wave = tid >> 6, lane = tid & 63;
    const int l31  = lane & 31, h = lane >> 5;
    const int wt   = wave & 1;            // t-half (32 t)
    const int wsx  = wave >> 1;           // s-half (32 s per iter)
    const int head = blockIdx.x & 31, tb = blockIdx.x >> 5;
    const int swq  = l31 & 7;

    const char* qsrc = ws + (size_t)head * 262144 + (size_t)tb * 8192;
    const char* ksrc = ws + 8388608  + (size_t)head * 262144;
    const char* vsrc = ws + 16777216 + (size_t)head * 262144;

    // prologue: Q (8 KB) + K tile0 + V tile0 (8 KB each), 2 chunks/wave each
#pragma unroll
    for (int n = 0; n < 2; ++n) {
        int ch = wave * 2 + n;
        async16(qsrc + ch * 1024 + lane * 16, Qs  + ch * 1024);
        async16(ksrc + ch * 1024 + lane * 16, Ks0 + ch * 1024);
        async16(vsrc + ch * 1024 + lane * 16, Vs0 + ch * 1024);
    }
    __syncthreads();

    // Q fragments (B operand): rows t = wt*32 + l31
    bf16x8 qf[4];
#pragma unroll
    for (int kb = 0; kb < 4; ++kb)
        qf[kb] = *(const bf16x8*)(Qs + (wt * 32 + l31) * 128
                                  + (((kb * 2 + h) ^ swq) << 4));

    f32x16 acc[2];                        // [ct] O^T[c][t] partial (s-half)
#pragma unroll
    for (int ct = 0; ct < 2; ++ct)
#pragma unroll
        for (int r = 0; r < 16; ++r) acc[ct][r] = 0.f;
    float lp = 0.f;

    for (int i = 0; i < 32; ++i) {
        const int cur = i & 1, nxt = cur ^ 1;
        if (i) __syncthreads();
        if (i < 31) {                     // prefetch tile i+1
            const char* kg = ksrc + (size_t)(i + 1) * 8192;
            const char* vg = vsrc + (size_t)(i + 1) * 8192;
            char* kd = Ks0 + nxt * 8192;
            char* vd = Vs0 + nxt * 8192;
#pragma unroll
            for (int n = 0; n < 2; ++n) {
                int ch = wave * 2 + n;
                async16(kg + ch * 1024 + lane * 16, kd + ch * 1024);
                async16(vg + ch * 1024 + lane * 16, vd + ch * 1024);
            }
        }
        const char* KsB = Ks0 + cur * 8192;
        const char* VsB = Vs0 + cur * 8192;

        // ---- QK^T (A=K): S^T rows s = wsx*32+pat, cols t (Q pre-scaled 1/8)
        f32x16 sc;
#pragma unroll
        for (int r = 0; r < 16; ++r) sc[r] = 0.f;
        const int krow = (wsx * 32 + l31) * 128;
#pragma unroll
        for (int kb = 0; kb < 4; ++kb) {
            bf16x8 kf = *(const bf16x8*)(KsB + krow + (((kb * 2 + h) ^ swq) << 4));
            sc = __builtin_amdgcn_mfma_f32_32x32x16_bf16(kf, qf[kb], sc, 0, 0, 0);
        }

        // ---- softmax (no max-sub; |score|<=~8) + bf16 truncation pack;
        //      l accumulated from TRUNCATED values so weights sum exactly
        unsigned p0[8];
#pragma unroll
        for (int d = 0; d < 8; ++d) {
            unsigned a0 = __float_as_uint(__expf(sc[2 * d]))     & 0xffff0000u;
            unsigned a1 = __float_as_uint(__expf(sc[2 * d + 1])) & 0xffff0000u;
            lp += __uint_as_float(a0) + __uint_as_float(a1);
            p0[d] = __builtin_amdgcn_perm(a1, a0, 0x07060302u);
        }

        // ---- xor-32 exchange: C-layout -> B-layout
        unsigned u00 = __shfl_xor(h ? p0[0] : p0[2], 32);
        unsigned u01 = __shfl_xor(h ? p0[1] : p0[3], 32);
        unsigned u02 = __shfl_xor(h ? p0[4] : p0[6], 32);
        unsigned u03 = __shfl_xor(h ? p0[5] : p0[7], 32);
        union PF { unsigned u[4]; bf16x8 v; };
        PF f00, f01;                      // [kb2i]
        f00.u[0] = h ? u00 : p0[0]; f00.u[1] = h ? u01 : p0[1];
        f00.u[2] = h ? p0[2] : u00; f00.u[3] = h ? p0[3] : u01;
        f01.u[0] = h ? u02 : p0[4]; f01.u[1] = h ? u03 : p0[5];
        f01.u[2] = h ? p0[6] : u02; f01.u[3] = h ? p0[7] : u03;

        // ---- PV: O^T[c][t] += V[c][s] * P[t][s] over this wave's 32 s
#pragma unroll
        for (int kb2i = 0; kb2i < 2; ++kb2i) {
            const bf16x8 pfv = kb2i ? f01.v : f00.v;
#pragma unroll
            for (int ct = 0; ct < 2; ++ct) {
                bf16x8 vf = *(const bf16x8*)(VsB + (ct * 32 + l31) * 128
                              + (((wsx * 4 + kb2i * 2 + h) ^ swq) << 4));
                acc[ct] = __builtin_amdgcn_mfma_f32_32x32x16_bf16(vf, pfv, acc[ct], 0, 0, 0);
            }
        }
    }

    __syncthreads();                      // all LDS compute reads done

    // ---- l: reduce over h, publish per s-half (Lb aliases dead Vs)
    float lt = lp + __shfl_xor(lp, 32);
    if (h == 0) Lb[wsx * 64 + wt * 32 + l31] = lt;
    // ---- O: s-half-1 waves stash partials (Ob aliases dead Ks)
    if (wsx == 1) {
#pragma unroll
        for (int ct = 0; ct < 2; ++ct)
#pragma unroll
            for (int r = 0; r < 16; ++r) {
                int c = ct * 32 + (r & 3) + 8 * (r >> 2) + 4 * h;
                Ob[c * 64 + wt * 32 + l31] = acc[ct][r];
            }
    }
    __syncthreads();

    if (wsx == 0) {
        const float li = 1.0f / (Lb[wt * 32 + l31] + Lb[64 + wt * 32 + l31]);
#pragma unroll
        for (int ct = 0; ct < 2; ++ct)
#pragma unroll
            for (int r = 0; r < 16; ++r) {
                int c = ct * 32 + (r & 3) + 8 * (r >> 2) + 4 * h;
                float v = acc[ct][r] + Ob[c * 64 + wt * 32 + l31];
                out[((size_t)head * 64 + c) * T_LEN + tb * 64 + wt * 32 + l31]
                    = v * li;
            }
    }
}

extern "C" void kernel_launch(void* const* d_in, const int* in_sizes, int n_in,
                              void* d_out, int out_size, void* d_ws, size_t ws_size,
                              hipStream_t stream) {
    const float* qkv = (const float*)d_in[0];
    float* out = (float*)d_out;
    char* ws = (char*)d_ws;   // 24 MB
    hipLaunchKernelGGL(prepack, dim3(2048), dim3(256), 0, stream, qkv, ws);
    hipLaunchKernelGGL(attn_fwd, dim3(1024), dim3(256), 0, stream, ws, out);
}

// Round 6
// 135.511 us; speedup vs baseline: 1.0904x; 1.0197x over previous
//
#include <hip/hip_runtime.h>
#include <stdint.h>

#define T_LEN 2048
#define QSCALE 0.125f   // softmax scale folded into Q at prepack (exact pow2)

typedef __attribute__((ext_vector_type(8))) short bf16x8;
typedef __attribute__((ext_vector_type(16))) float f32x16;

// RNE fp32 pair -> packed bf16x2 (inputs finite normals)
static __device__ __forceinline__ unsigned pack_bf16(float a, float b) {
    unsigned ua = __float_as_uint(a);
    unsigned ub = __float_as_uint(b);
    ua = (ua + 0x7fffu + ((ua >> 16) & 1u)) >> 16;
    ub = (ub + 0x7fffu + ((ub >> 16) & 1u));
    return (ua & 0xffffu) | (ub & 0xffff0000u);
}

// async global->LDS DMA, 16 B/lane: LDS dest = wave-uniform base + lane*16
static __device__ __forceinline__ void async16(const void* g, void* l) {
    __builtin_amdgcn_global_load_lds(
        (const __attribute__((address_space(1))) unsigned int*)g,
        (__attribute__((address_space(3))) unsigned int*)l, 16, 0, 0);
}

// ---------------------------------------------------------------------------
// Prepack:
//   Q: ws+0     bf16 [head][t][swz c] rows 128B, scaled by QSCALE
//   K: ws+8MB   bf16 [head][s][swz c] rows 128B
//   V: ws+16MB  bf16 [head][sTile(64)][c][swz s] rows 128B
// LDS transpose tile stride 129 floats (2-way worst -> free). Phase 2 is
// shuffle-free: each thread owns a c-pair (rows 2cp,2cp+1) and packs locally.
// ---------------------------------------------------------------------------
__global__ __launch_bounds__(256)
void prepack(const float* __restrict__ qkv, char* __restrict__ ws)
{
    __shared__ float tile[64 * 129];
    const int tid = threadIdx.x;
    const int b = blockIdx.x;

    if (b < 1024) {                       // ---- Q / K transpose (128 t x 64 c)
        const int isK  = b >> 9;
        const int bb   = b & 511;
        const int head = bb >> 4, chunk = bb & 15;
        const float* src = qkv + (size_t)head * 192 * T_LEN
                               + (isK ? (size_t)64 * T_LEN : 0);
        const int t0 = chunk * 128;
        const float scale = isK ? 1.0f : QSCALE;
#pragma unroll
        for (int i = 0; i < 8; ++i) {
            int p = i * 256 + tid;
            int c = p >> 5, t4 = p & 31;
            float4 v = *(const float4*)(src + (size_t)c * T_LEN + t0 + 4 * t4);
            *(float4*)&tile[c * 129 + ((t4 ^ (c & 7)) << 2)] = v;
        }
        __syncthreads();
        unsigned* dst = (unsigned*)ws + (size_t)isK * 2097152
                      + (size_t)head * 65536 + (size_t)t0 * 32;
        const int cp = tid & 31;          // c-pair: rows 2cp, 2cp+1
        const int jg = tid >> 5;          // 0..7
        const int c0 = 2 * cp, c1 = 2 * cp + 1;
#pragma unroll
        for (int ii = 0; ii < 4; ++ii) {
            int j = ii * 8 + jg;          // t-chunk 0..31 (4 t each)
            float4 m0 = *(const float4*)&tile[c0 * 129 + ((j ^ (c0 & 7)) << 2)];
            float4 m1 = *(const float4*)&tile[c1 * 129 + ((j ^ (c1 & 7)) << 2)];
            unsigned d0 = pack_bf16(m0.x * scale, m1.x * scale);
            unsigned d1 = pack_bf16(m0.y * scale, m1.y * scale);
            unsigned d2 = pack_bf16(m0.z * scale, m1.z * scale);
            unsigned d3 = pack_bf16(m0.w * scale, m1.w * scale);
            int t = 4 * j;
            dst[t * 32 + (((cp >> 2) ^ (t & 7)) << 2) + (cp & 3)] = d0; ++t;
            dst[t * 32 + (((cp >> 2) ^ (t & 7)) << 2) + (cp & 3)] = d1; ++t;
            dst[t * 32 + (((cp >> 2) ^ (t & 7)) << 2) + (cp & 3)] = d2; ++t;
            dst[t * 32 + (((cp >> 2) ^ (t & 7)) << 2) + (cp & 3)] = d3;
        }
    } else {                              // ---- V pass-through (swizzle only)
        const int b3 = b - 1024;
        const int head = b3 >> 5, st = b3 & 31;
        const float* src = qkv + (size_t)head * 192 * T_LEN + (size_t)128 * T_LEN;
        const int s0 = st * 64;
        unsigned* dst = (unsigned*)(ws + 16777216) + (size_t)b3 * 2048;
#pragma unroll
        for (int i = 0; i < 8; ++i) {
            int p = i * 256 + tid;
            int s2 = p & 31, cc = p >> 5;
            float2 v = *(const float2*)(src + (size_t)cc * T_LEN + s0 + 2 * s2);
            dst[cc * 32 + (((s2 >> 2) ^ (cc & 7)) << 2) + (s2 & 3)] = pack_bf16(v.x, v.y);
        }
    }
}

// ---------------------------------------------------------------------------
// Main: flash attention, 32x32x16 MFMA, S^T orientation, register-only P
// transform (xor-32 exchange). TTILE=64, STILE=64, 1024 blocks.
// 32 KB LDS (V buf1 aliases dead Qs) -> 5-block/CU LDS capacity, 4+ resident.
// 2t x 2s wave split, double-buffered K/V via async DMA. All 32 blocks of a
// head share bid%8 -> head K/V pinned to one XCD L2.
// ---------------------------------------------------------------------------
__global__ __launch_bounds__(256, 5)
void attn_fwd(const char* __restrict__ ws, float* __restrict__ out)
{
    __shared__ char smem[32768];
    // [0,8192)       Qs (dead after qf) = Vs[1]
    // [8192,24576)   Ks[0],Ks[1]   (epilogue: Ob 16 KB)
    // [24576,32768)  Vs[0]         (epilogue: Lb 512 B)
    char*  Qs  = smem;
    char*  Ks0 = smem + 8192;
    char*  Vs0 = smem + 24576;
    float* Ob  = (float*)(smem + 8192);
    float* Lb  = (float*)(smem + 24576);

    const int tid  = threadIdx.x;
    const int wave = tid >> 6, lane = tid & 63;
    const int l31  = lane & 31, h = lane >> 5;
    const int wt   = wave & 1;            // t-half (32 t)
    const int wsx  = wave >> 1;           // s-half (32 s per iter)
    const int head = blockIdx.x & 31, tb = blockIdx.x >> 5;
    const int swq  = l31 & 7;

    const char* qsrc = ws + (size_t)head * 262144 + (size_t)tb * 8192;
    const char* ksrc = ws + 8388608  + (size_t)head * 262144;
    const char* vsrc = ws + 16777216 + (size_t)head * 262144;

    // prologue: Q (8 KB) + K tile0 + V tile0 (8 KB each), 2 chunks/wave each
#pragma unroll
    for (int n = 0; n < 2; ++n) {
        int ch = wave * 2 + n;
        async16(qsrc + ch * 1024 + lane * 16, Qs  + ch * 1024);
        async16(ksrc + ch * 1024 + lane * 16, Ks0 + ch * 1024);
        async16(vsrc + ch * 1024 + lane * 16, Vs0 + ch * 1024);
    }
    __syncthreads();

    // Q fragments (B operand): rows t = wt*32 + l31
    bf16x8 qf[4];
#pragma unroll
    for (int kb = 0; kb < 4; ++kb)
        qf[kb] = *(const bf16x8*)(Qs + (wt * 32 + l31) * 128
                                  + (((kb * 2 + h) ^ swq) << 4));
    __syncthreads();                      // all qf read before V1 DMA into Qs

    f32x16 acc[2];                        // [ct] O^T[c][t] partial (s-half)
#pragma unroll
    for (int ct = 0; ct < 2; ++ct)
#pragma unroll
        for (int r = 0; r < 16; ++r) acc[ct][r] = 0.f;
    float lpx = 0.f, lpy = 0.f;

    for (int i = 0; i < 32; ++i) {
        const int cur = i & 1, nxt = cur ^ 1;
        if (i) __syncthreads();
        if (i < 31) {                     // prefetch tile i+1
            const char* kg = ksrc + (size_t)(i + 1) * 8192;
            const char* vg = vsrc + (size_t)(i + 1) * 8192;
            char* kd = Ks0 + nxt * 8192;
            char* vd = nxt ? Qs : Vs0;
#pragma unroll
            for (int n = 0; n < 2; ++n) {
                int ch = wave * 2 + n;
                async16(kg + ch * 1024 + lane * 16, kd + ch * 1024);
                async16(vg + ch * 1024 + lane * 16, vd + ch * 1024);
            }
        }
        const char* KsB = Ks0 + cur * 8192;
        const char* VsB = cur ? Qs : Vs0;

        // ---- QK^T (A=K): S^T rows s = wsx*32+pat, cols t (Q pre-scaled 1/8)
        f32x16 sc;
#pragma unroll
        for (int r = 0; r < 16; ++r) sc[r] = 0.f;
        const int krow = (wsx * 32 + l31) * 128;
#pragma unroll
        for (int kb = 0; kb < 4; ++kb) {
            bf16x8 kf = *(const bf16x8*)(KsB + krow + (((kb * 2 + h) ^ swq) << 4));
            sc = __builtin_amdgcn_mfma_f32_32x32x16_bf16(kf, qf[kb], sc, 0, 0, 0);
        }

        // ---- softmax (no max-sub; |score|<=~8). P packed by perm-truncation
        //      straight from raw exp bits; l accumulates unrounded exps
        //      (0.2% trunc bias on P cancels to ~5e-4 absolute in the ratio).
        unsigned p0[8];
#pragma unroll
        for (int d = 0; d < 8; ++d) {
            float e0 = __expf(sc[2 * d]);
            float e1 = __expf(sc[2 * d + 1]);
            lpx += e0;
            lpy += e1;
            p0[d] = __builtin_amdgcn_perm(__float_as_uint(e1),
                                          __float_as_uint(e0), 0x07060302u);
        }

        // ---- xor-32 exchange: C-layout -> B-layout
        unsigned u00 = __shfl_xor(h ? p0[0] : p0[2], 32);
        unsigned u01 = __shfl_xor(h ? p0[1] : p0[3], 32);
        unsigned u02 = __shfl_xor(h ? p0[4] : p0[6], 32);
        unsigned u03 = __shfl_xor(h ? p0[5] : p0[7], 32);
        union PF { unsigned u[4]; bf16x8 v; };
        PF f00, f01;                      // [kb2i]
        f00.u[0] = h ? u00 : p0[0]; f00.u[1] = h ? u01 : p0[1];
        f00.u[2] = h ? p0[2] : u00; f00.u[3] = h ? p0[3] : u01;
        f01.u[0] = h ? u02 : p0[4]; f01.u[1] = h ? u03 : p0[5];
        f01.u[2] = h ? p0[6] : u02; f01.u[3] = h ? p0[7] : u03;

        // ---- PV: O^T[c][t] += V[c][s] * P[t][s] over this wave's 32 s
#pragma unroll
        for (int kb2i = 0; kb2i < 2; ++kb2i) {
            const bf16x8 pfv = kb2i ? f01.v : f00.v;
#pragma unroll
            for (int ct = 0; ct < 2; ++ct) {
                bf16x8 vf = *(const bf16x8*)(VsB + (ct * 32 + l31) * 128
                              + (((wsx * 4 + kb2i * 2 + h) ^ swq) << 4));
                acc[ct] = __builtin_amdgcn_mfma_f32_32x32x16_bf16(vf, pfv, acc[ct], 0, 0, 0);
            }
        }
    }

    __syncthreads();                      // all LDS compute reads done

    // ---- l: reduce over h, publish per s-half (Lb aliases dead Vs0)
    float lp = lpx + lpy;
    float lt = lp + __shfl_xor(lp, 32);
    if (h == 0) Lb[wsx * 64 + wt * 32 + l31] = lt;
    // ---- O: s-half-1 waves stash partials (Ob aliases dead Ks)
    if (wsx == 1) {
#pragma unroll
        for (int ct = 0; ct < 2; ++ct)
#pragma unroll
            for (int r = 0; r < 16; ++r) {
                int c = ct * 32 + (r & 3) + 8 * (r >> 2) + 4 * h;
                Ob[c * 64 + wt * 32 + l31] = acc[ct][r];
            }
    }
    __syncthreads();

    if (wsx == 0) {
        const float li = 1.0f / (Lb[wt * 32 + l31] + Lb[64 + wt * 32 + l31]);
#pragma unroll
        for (int ct = 0; ct < 2; ++ct)
#pragma unroll
            for (int r = 0; r < 16; ++r) {
                int c = ct * 32 + (r & 3) + 8 * (r >> 2) + 4 * h;
                float v = acc[ct][r] + Ob[c * 64 + wt * 32 + l31];
                out[((size_t)head * 64 + c) * T_LEN + tb * 64 + wt * 32 + l31]
                    = v * li;
            }
    }
}

extern "C" void kernel_launch(void* const* d_in, const int* in_sizes, int n_in,
                              void* d_out, int out_size, void* d_ws, size_t ws_size,
                              hipStream_t stream) {
    const float* qkv = (const float*)d_in[0];
    float* out = (float*)d_out;
    char* ws = (char*)d_ws;   // 24 MB
    hipLaunchKernelGGL(prepack, dim3(2048), dim3(256), 0, stream, qkv, ws);
    hipLaunchKernelGGL(attn_fwd, dim3(1024), dim3(256), 0, stream, ws, out);
}